// Round 18
// baseline (157.075 us; speedup 1.0000x reference)
//
#include <hip/hip_runtime.h>
#include <hip/hip_bf16.h>

// B=4, S=2048, D=1024, E=8, H=512, top-2 + shared expert
#define TOKENS 8192
#define D_DIM  1024
#define E_NUM  8
#define H_DIM  512
#define N1     4608            // E*H + H (Bt1 rows)
#define CAP    3072            // per-expert row capacity (~2048 expected, +26 sigma)
#define ET256  (CAP / 256)     // 12 tiles of 256 per expert segment
#define ET128  (CAP / 128)     // 24 tiles of 128 per expert segment
#define EXP_ROWS (E_NUM * CAP) // 24576 expert rows
#define SH_BASE  EXP_ROWS      // shared segment base in Hs row space
#define HS_ROWS (EXP_ROWS + TOKENS)  // 32768

typedef __bf16 bf16_t;
typedef __bf16 bf16x8 __attribute__((ext_vector_type(8)));
typedef __bf16 bf16x4 __attribute__((ext_vector_type(4)));
typedef float  f32x4  __attribute__((ext_vector_type(4)));

// tanh-form GELU, 7 VALU ops
__device__ __forceinline__ float gelu_fast(float v) {
  float w = v * v;
  float t = __builtin_fmaf(w, 0.10294307f, 2.30258835f);
  float z = v * t;
  float e = __builtin_amdgcn_exp2f(z);
  float r = __builtin_amdgcn_rcpf(e + 1.0f);
  return v - v * r;
}

// ---------------------------------------------------------------- routing (+ fused cast + fused weight repack)
// Dot loop float4-vectorized; x read ONCE (cast reuses the same registers).
// fp64 accumulation kept (selection matches fp64-score top-2; order-noise ~1e-16).
// Tail uses sigmoid monotonicity: fp64 compares only; weights = sig1/(sig1+sig2).
__global__ __launch_bounds__(256) void routing_repack_kernel(
    const float* __restrict__ x, const float* __restrict__ gW,
    const float* __restrict__ route_scale, float* __restrict__ gateT,
    int* __restrict__ sel, bf16_t* __restrict__ Xb,
    const float* __restrict__ W1, const float* __restrict__ Ws1,
    const float* __restrict__ W2, const float* __restrict__ Ws2,
    bf16_t* __restrict__ Bt1, bf16_t* __restrict__ Bt2e) {
  const int bid = blockIdx.x;
  if (bid < TOKENS / 4) {
    int tok  = bid * 4 + (threadIdx.x >> 6);
    int lane = threadIdx.x & 63;
    const float* xr = x + (size_t)tok * D_DIM;
    const float4* x4 = (const float4*)xr;
    bf16x4* xb4 = (bf16x4*)(Xb + (size_t)tok * D_DIM);
    double p[E_NUM];
#pragma unroll
    for (int e = 0; e < E_NUM; ++e) p[e] = 0.0;
#pragma unroll
    for (int i = 0; i < 4; ++i) {
      const int idx = i * 64 + lane;          // float4 index; d0 = idx*4
      const float4 xv = x4[idx];
      const float4* g0 = (const float4*)(gW + (size_t)idx * 32);  // 4 rows x 8 floats
      float4 gv[8];
#pragma unroll
      for (int j = 0; j < 8; ++j) gv[j] = g0[j];
      const float xs[4] = { xv.x, xv.y, xv.z, xv.w };
#pragma unroll
      for (int k = 0; k < 4; ++k) {
        const double xd = (double)xs[k];
        const float4 a = gv[2 * k], b = gv[2 * k + 1];
        p[0] += xd * (double)a.x; p[1] += xd * (double)a.y;
        p[2] += xd * (double)a.z; p[3] += xd * (double)a.w;
        p[4] += xd * (double)b.x; p[5] += xd * (double)b.y;
        p[6] += xd * (double)b.z; p[7] += xd * (double)b.w;
      }
      bf16x4 o = { (bf16_t)xv.x, (bf16_t)xv.y, (bf16_t)xv.z, (bf16_t)xv.w };
      xb4[idx] = o;
    }
#pragma unroll
    for (int off = 32; off > 0; off >>= 1) {
#pragma unroll
      for (int e = 0; e < E_NUM; ++e) p[e] += __shfl_xor(p[e], off, 64);
    }
    if (lane == 0) {
      const float rs = route_scale[0];
      const bool neg = rs < 0.f;     // sigmoid strictly increasing; rs<0 flips order
      int i1 = 0;
#pragma unroll
      for (int e = 1; e < E_NUM; ++e)
        if (neg ? (p[e] < p[i1]) : (p[e] > p[i1])) i1 = e;
      int i2 = (i1 == 0) ? 1 : 0;
#pragma unroll
      for (int e = 0; e < E_NUM; ++e)
        if (e != i1 && (neg ? (p[e] < p[i2]) : (p[e] > p[i2]))) i2 = e;
      const float s1 = 1.f / (1.f + __expf(-(float)p[i1]));
      const float s2 = 1.f / (1.f + __expf(-(float)p[i2]));
      const float inv = 1.f / (s1 + s2);
      float o[E_NUM];
#pragma unroll
      for (int e = 0; e < E_NUM; ++e) o[e] = 0.f;
      o[i1] = s1 * inv;
      o[i2] = s2 * inv;
#pragma unroll
      for (int e = 0; e < E_NUM; ++e) gateT[(size_t)e * TOKENS + tok] = o[e];
      sel[tok] = i1 * 8 + i2;
    }
  } else {
    __shared__ float tile[32][33];
    const int rid = bid - TOKENS / 4;
    const int bx = rid & 31, by = rid >> 5;   // 32 x-blocks, 288 y-blocks
    const int tx = threadIdx.x & 31, ty = threadIdx.x >> 5;
    if (by < 144) {
      const int k0 = bx * 32, n0 = by * 32;
#pragma unroll
      for (int i = 0; i < 4; ++i) {
        int kl = ty + i * 8;
        int n = n0 + tx, k = k0 + kl;
        float v;
        if (n0 < 4096) v = W1[(size_t)(n >> 9) * (D_DIM * H_DIM) + (size_t)k * H_DIM + (n & 511)];
        else           v = Ws1[(size_t)k * H_DIM + (n - 4096)];
        tile[kl][tx] = v;
      }
      __syncthreads();
#pragma unroll
      for (int i = 0; i < 4; ++i) {
        int nl = ty + i * 8;
        Bt1[(size_t)(n0 + nl) * D_DIM + k0 + tx] = (bf16_t)tile[tx][nl];
      }
    } else {
      const int yy = by - 144;
      const int e = yy >> 4;                 // 0..8
      const int h0 = (yy & 15) * 32;
      const int d0 = bx * 32;
#pragma unroll
      for (int i = 0; i < 4; ++i) {
        int hl = ty + i * 8;
        int h = h0 + hl, d = d0 + tx;
        float v = (e < E_NUM) ? W2[((size_t)e * H_DIM + h) * D_DIM + d]
                              : Ws2[(size_t)h * D_DIM + d];
        tile[hl][tx] = v;
      }
      __syncthreads();
#pragma unroll
      for (int i = 0; i < 4; ++i) {
        int dl = ty + i * 8;
        Bt2e[((size_t)e * D_DIM + (d0 + dl)) * H_DIM + h0 + tx] = (bf16_t)tile[tx][dl];
      }
    }
  }
}

// ---------------------------------------------------------------- list build: 8 blocks (1/expert) x 256, pads to x256
__global__ __launch_bounds__(256) void listbuild_kernel(
    const float* __restrict__ gateT, const int* __restrict__ sel,
    int* __restrict__ perm, float* __restrict__ grow,
    int* __restrict__ tok2row, int* __restrict__ padcnt) {
  const int e = blockIdx.x;
  const int tid = threadIdx.x, lane = tid & 63, wid = tid >> 6;
  __shared__ int wsum[4];
  const float* row = gateT + (size_t)e * TOKENS;
  const int base = e * CAP;
  int running = 0;
  float gv = row[tid];                       // prefetch chunk 0
  for (int c = 0; c < TOKENS / 256; ++c) {
    float gv_next = (c + 1 < TOKENS / 256) ? row[(c + 1) * 256 + tid] : 0.f;
    const int tok = c * 256 + tid;
    const bool f = gv > 0.f;
    unsigned long long m = __ballot(f);
    int lanepre = __popcll(m & ((1ull << lane) - 1ull));
    if (lane == 0) wsum[wid] = __popcll(m);
    __syncthreads();
    int wbase = 0;
#pragma unroll
    for (int w2 = 0; w2 < 4; ++w2) if (w2 < wid) wbase += wsum[w2];
    const int tot = wsum[0] + wsum[1] + wsum[2] + wsum[3];
    if (f) {
      const int idx = running + wbase + lanepre;
      if (idx < CAP) {
        perm[base + idx] = tok;
        grow[base + idx] = gv;
        const int s = sel[tok];
        const int other = ((s >> 3) == e) ? (s & 7) : (s >> 3);
        tok2row[tok * 2 + (e > other ? 1 : 0)] = base + idx;
      }
    }
    running += tot;
    __syncthreads();
    gv = gv_next;
  }
  if (running > CAP) running = CAP;
  const int pc = (running + 255) & ~255;     // pad to 256-row tiles (valid for 128-tiles too)
  for (int i = running + tid; i < pc; i += 256) { perm[base + i] = 0; grow[base + i] = 0.f; }
  if (tid == 0) padcnt[e] = pc;
}

__device__ __forceinline__ void gload16(const char* src, char* dst) {
  __builtin_amdgcn_global_load_lds((const __attribute__((address_space(1))) void*)src,
      (__attribute__((address_space(3))) void*)dst, 16, 0, 0);
}

// staging source column byte with slot pre-swizzle (inverse of read swizzle)
__device__ __forceinline__ int swz_src(int lane) {
  return ((lane & 7) ^ ((lane >> 3) & 7)) * 16;
}

// ---------------------------------------------------------------- 256x256 BK=64 8-wave GEMM core (round-11 proven)
__device__ __forceinline__ void gemm_core256(
    const char* ga0, const char* ga1, const char* ga2, const char* ga3,
    const char* gb0, const char* gb1, const char* gb2, const char* gb3,
    int ktiles, char* lds, int wid, int lane, f32x4 (&acc)[8][4]) {
  const int wm = wid >> 2, wn = wid & 3;
  const int lA = lane & 15, kq = lane >> 4;
  const int slot0 = (kq ^ (lA & 7)) * 16;
  const int slot1 = ((4 + kq) ^ (lA & 7)) * 16;

  auto stage8 = [&](int buf, int t) {
    char* dA = lds + buf * 65536 + wid * 1024;
    char* dB = dA + 32768;
    const size_t ko = (size_t)t * 128;
    gload16(ga0 + ko, dA + 0 * 8192);
    gload16(ga1 + ko, dA + 1 * 8192);
    gload16(ga2 + ko, dA + 2 * 8192);
    gload16(ga3 + ko, dA + 3 * 8192);
    gload16(gb0 + ko, dB + 0 * 8192);
    gload16(gb1 + ko, dB + 1 * 8192);
    gload16(gb2 + ko, dB + 2 * 8192);
    gload16(gb3 + ko, dB + 3 * 8192);
  };

  stage8(0, 0);
  for (int t = 0; t < ktiles; ++t) {
    const int b = t & 1;
    asm volatile("s_waitcnt vmcnt(0)" ::: "memory");   // tile-t loads landed (issued 1 tile ago)
    __builtin_amdgcn_s_barrier();                      // landed for ALL waves; t-1 readers retired
    asm volatile("" ::: "memory");
    if (t + 1 < ktiles) stage8(b ^ 1, t + 1);
    const char* Ab = lds + b * 65536 + wm * 16384;
    const char* Bb = lds + b * 65536 + 32768 + (wn >> 1) * 16384 + ((wn & 1) * 64) * 128;
    bf16x8 bfv[4][2];
#pragma unroll
    for (int nf = 0; nf < 4; ++nf) {
      const int rb = (nf * 16 + lA) * 128;
      bfv[nf][0] = *(const bf16x8*)(Bb + rb + slot0);
      bfv[nf][1] = *(const bf16x8*)(Bb + rb + slot1);
    }
#pragma unroll
    for (int qm = 0; qm < 2; ++qm) {
      bf16x8 af[4][2];
#pragma unroll
      for (int i = 0; i < 4; ++i) {
        const int ra = ((qm * 4 + i) * 16 + lA) * 128;
        af[i][0] = *(const bf16x8*)(Ab + ra + slot0);
        af[i][1] = *(const bf16x8*)(Ab + ra + slot1);
      }
      __builtin_amdgcn_s_setprio(1);
#pragma unroll
      for (int s = 0; s < 2; ++s)
#pragma unroll
        for (int i = 0; i < 4; ++i)
#pragma unroll
          for (int nf = 0; nf < 4; ++nf)
            acc[qm * 4 + i][nf] = __builtin_amdgcn_mfma_f32_16x16x32_bf16(
                af[i][s], bfv[nf][s], acc[qm * 4 + i][nf], 0, 0, 0);
      __builtin_amdgcn_s_setprio(0);
      __builtin_amdgcn_sched_barrier(0);
    }
  }
}

// ---------------------------------------------------------------- 128x256 BK=64 8-wave core (gemm2e / gemm2s)
__device__ __forceinline__ void gemm_core_s(
    const char* ga, const char* gb,        // per-lane row ptrs, stride 1024B
    int ktiles, char* lds, int wid, int lane, f32x4 (&acc)[4][4]) {
  const int wm = wid >> 2, wn = wid & 3;
  const int lA = lane & 15, kq = lane >> 4;
  const int slot0 = (kq ^ (lA & 7)) * 16;
  const int slot1 = ((4 + kq) ^ (lA & 7)) * 16;

  auto stage6 = [&](int buf, int t) {
    char* base = lds + buf * 49152;
    char* dA = base + wid * 2048;
    char* dB = base + 16384 + wid * 4096;
    const size_t ko = (size_t)t * 128;
    gload16(ga + ko,         dA);
    gload16(ga + 8192 + ko,  dA + 1024);
    gload16(gb + ko,         dB);
    gload16(gb + 8192 + ko,  dB + 1024);
    gload16(gb + 16384 + ko, dB + 2048);
    gload16(gb + 24576 + ko, dB + 3072);
  };

  stage6(0, 0);
  for (int t = 0; t < ktiles; ++t) {
    const int b = t & 1;
    asm volatile("s_waitcnt vmcnt(0)" ::: "memory");
    __builtin_amdgcn_s_barrier();
    asm volatile("" ::: "memory");
    if (t + 1 < ktiles) stage6(b ^ 1, t + 1);
    const char* Ab = lds + b * 49152 + wm * 8192;            // wm*64 rows * 128B
    const char* Bb = lds + b * 49152 + 16384 + wn * 8192;    // wn*64 n-rows * 128B
    bf16x8 bfv[4][2];
#pragma unroll
    for (int nf = 0; nf < 4; ++nf) {
      const int rb = (nf * 16 + lA) * 128;
      bfv[nf][0] = *(const bf16x8*)(Bb + rb + slot0);
      bfv[nf][1] = *(const bf16x8*)(Bb + rb + slot1);
    }
#pragma unroll
    for (int qm = 0; qm < 2; ++qm) {
      bf16x8 af[2][2];
#pragma unroll
      for (int i = 0; i < 2; ++i) {
        const int ra = ((qm * 2 + i) * 16 + lA) * 128;
        af[i][0] = *(const bf16x8*)(Ab + ra + slot0);
        af[i][1] = *(const bf16x8*)(Ab + ra + slot1);
      }
      __builtin_amdgcn_s_setprio(1);
#pragma unroll
      for (int s = 0; s < 2; ++s)
#pragma unroll
        for (int i = 0; i < 2; ++i)
#pragma unroll
          for (int nf = 0; nf < 4; ++nf)
            acc[qm * 2 + i][nf] = __builtin_amdgcn_mfma_f32_16x16x32_bf16(
                af[i][s], bfv[nf][s], acc[qm * 2 + i][nf], 0, 0, 0);
      __builtin_amdgcn_s_setprio(0);
      __builtin_amdgcn_sched_barrier(0);
    }
  }
}

// ---------------------------------------------------------------- GEMM1 (256x256): Hs = gate * gelu(X[perm] @ W1[e]^T + b1)
__global__ __launch_bounds__(512, 2) void gemm1e_kernel(
    const bf16_t* __restrict__ Xb, const bf16_t* __restrict__ Bt1,
    const int* __restrict__ perm, const float* __restrict__ grow,
    const int* __restrict__ padcnt,
    const float* __restrict__ b1, const float* __restrict__ bs1,
    bf16_t* __restrict__ Hs) {
  __shared__ bf16_t sL[65536];           // 128 KB
  const int t = threadIdx.x, wid = t >> 6, lane = t & 63;
  // T1 XCD-bijective swizzle: grid 2x128 = 256 = 8 XCDs x 32.
  const int L = blockIdx.x + 2 * blockIdx.y;
  const int xc = L & 7, ii = L >> 3;
  const int bx = xc >> 2;
  const int by = (xc & 3) * 32 + ii;
  int e, rowbase;
  if (by < E_NUM * ET256) {
    e = by / ET256;
    const int lt = by - e * ET256;
    if (lt * 256 >= padcnt[e]) return;
    rowbase = e * CAP + lt * 256;
  } else {
    e = E_NUM;
    rowbase = SH_BASE + (by - E_NUM * ET256) * 256;
  }
  const int n0 = bx * 256;               // N = 512
  const int rl = wid * 8 + (lane >> 3);
  const int sc = swz_src(lane);
  const char *ga[4], *gb[4];
#pragma unroll
  for (int g = 0; g < 4; ++g) {
    const int r = g * 64 + rl;
    const int tok = (e < E_NUM) ? perm[rowbase + r] : (rowbase - SH_BASE + r);
    ga[g] = (const char*)Xb + (size_t)tok * 2048 + sc;
    gb[g] = (const char*)(Bt1 + (size_t)e * H_DIM * D_DIM) + (size_t)(n0 + r) * 2048 + sc;
  }
  f32x4 acc[8][4];
#pragma unroll
  for (int i = 0; i < 8; ++i)
#pragma unroll
    for (int j = 0; j < 4; ++j) acc[i][j] = (f32x4){0.f, 0.f, 0.f, 0.f};
  gemm_core256(ga[0], ga[1], ga[2], ga[3], gb[0], gb[1], gb[2], gb[3],
               D_DIM / 64, (char*)sL, wid, lane, acc);

  const int wm = wid >> 2, wn = wid & 3, lA = lane & 15;
  const float* bias = (e < E_NUM) ? (b1 + e * H_DIM) : bs1;
#pragma unroll
  for (int mf = 0; mf < 8; ++mf) {
    const int rloc = wm * 128 + mf * 16 + (lane >> 4) * 4;
    float gr[4];
#pragma unroll
    for (int q = 0; q < 4; ++q)
      gr[q] = (e < E_NUM) ? grow[rowbase + rloc + q] : 1.0f;
#pragma unroll
    for (int nf = 0; nf < 4; ++nf) {
      const int col = n0 + wn * 64 + nf * 16 + lA;
      const float bv = bias[col];
#pragma unroll
      for (int q = 0; q < 4; ++q) {
        float v = gelu_fast(acc[mf][nf][q] + bv);
        Hs[(size_t)(rowbase + rloc + q) * H_DIM + col] = (bf16_t)(v * gr[q]);
      }
    }
  }
}

// ---------------------------------------------------------------- GEMM2 expert tiles (128x256): Ys(bf16) = acc + grow*b2[e]
__global__ __launch_bounds__(512, 2) void gemm2e_kernel(
    const bf16_t* __restrict__ Hs, const bf16_t* __restrict__ Bt2e,
    const float* __restrict__ grow, const int* __restrict__ padcnt,
    const float* __restrict__ b2, bf16_t* __restrict__ Ys) {
  __shared__ bf16_t sL[49152];           // 96 KB
  const int t = threadIdx.x, wid = t >> 6, lane = t & 63;
  // T1 swizzle: grid 4x192 = 768 = 8 x 96
  const int L = blockIdx.x + 4 * blockIdx.y;
  const int xc = L & 7, ii = L >> 3;
  const int bx = xc >> 1;                // 0..3
  const int by = (xc & 1) * 96 + ii;     // 0..191
  const int e = by / ET128;
  const int lt = by - e * ET128;
  if (lt * 128 >= padcnt[e]) return;
  const int rowbase = e * CAP + lt * 128;
  const int n0 = bx * 256;               // N = 1024
  const int sc = swz_src(lane);
  const char* ga = (const char*)Hs + (size_t)(rowbase + wid * 16 + (lane >> 3)) * 1024 + sc;
  const char* gb = (const char*)(Bt2e + (size_t)e * D_DIM * H_DIM)
                 + (size_t)(n0 + wid * 32 + (lane >> 3)) * 1024 + sc;
  f32x4 acc[4][4];
#pragma unroll
  for (int i = 0; i < 4; ++i)
#pragma unroll
    for (int j = 0; j < 4; ++j) acc[i][j] = (f32x4){0.f, 0.f, 0.f, 0.f};
  gemm_core_s(ga, gb, H_DIM / 64, (char*)sL, wid, lane, acc);

  const int wm = wid >> 2, wn = wid & 3, lA = lane & 15;
  const float* bb = b2 + (size_t)e * D_DIM;
#pragma unroll
  for (int mf = 0; mf < 4; ++mf) {
    const int rloc = wm * 64 + mf * 16 + (lane >> 4) * 4;
    float gr[4];
#pragma unroll
    for (int q = 0; q < 4; ++q) gr[q] = grow[rowbase + rloc + q];
#pragma unroll
    for (int nf = 0; nf < 4; ++nf) {
      const int col = n0 + wn * 64 + nf * 16 + lA;
      const float bv = bb[col];
#pragma unroll
      for (int q = 0; q < 4; ++q)
        Ys[(size_t)(rowbase + rloc + q) * D_DIM + col] = (bf16_t)(acc[mf][nf][q] + gr[q] * bv);
    }
  }
}

// ---------------------------------------------------------------- GEMM2 shared tiles + combine (128x256 tile, 256 blocks)
__global__ __launch_bounds__(512, 2) void gemm2s_kernel(
    const bf16_t* __restrict__ Hs, const bf16_t* __restrict__ Bt2e,
    const int* __restrict__ tok2row, const float* __restrict__ bs2,
    const bf16_t* __restrict__ Ys, float* __restrict__ out) {
  __shared__ bf16_t sL[49152];           // 96 KB
  const int t = threadIdx.x, wid = t >> 6, lane = t & 63;
  // T1 swizzle: grid 4x64 = 256 = 8 x 32
  const int L = blockIdx.x + 4 * blockIdx.y;
  const int xc = L & 7, ii = L >> 3;
  const int bx = xc >> 1;                // 0..3
  const int by = (xc & 1) * 32 + ii;     // 0..63
  const int tokbase = by * 128;
  const int rowbase = SH_BASE + tokbase;
  const int n0 = bx * 256;               // N = 1024
  const int sc = swz_src(lane);
  const char* ga = (const char*)Hs + (size_t)(rowbase + wid * 16 + (lane >> 3)) * 1024 + sc;
  const char* gb = (const char*)(Bt2e + (size_t)E_NUM * D_DIM * H_DIM)
                 + (size_t)(n0 + wid * 32 + (lane >> 3)) * 1024 + sc;
  f32x4 acc[4][4];
#pragma unroll
  for (int i = 0; i < 4; ++i)
#pragma unroll
    for (int j = 0; j < 4; ++j) acc[i][j] = (f32x4){0.f, 0.f, 0.f, 0.f};
  gemm_core_s(ga, gb, H_DIM / 64, (char*)sL, wid, lane, acc);

  const int wm = wid >> 2, wn = wid & 3, lA = lane & 15;
#pragma unroll
  for (int mf = 0; mf < 4; ++mf) {
    const int rloc = wm * 64 + mf * 16 + (lane >> 4) * 4;
    int r0[4], r1[4];
#pragma unroll
    for (int q = 0; q < 4; ++q) {
      const int tok = tokbase + rloc + q;
      r0[q] = tok2row[tok * 2];
      r1[q] = tok2row[tok * 2 + 1];
    }
#pragma unroll
    for (int nf = 0; nf < 4; ++nf) {
      const int col = n0 + wn * 64 + nf * 16 + lA;
      const float bv = bs2[col];
#pragma unroll
      for (int q = 0; q < 4; ++q) {
        const int tok = tokbase + rloc + q;
        float y0 = (float)Ys[(size_t)r0[q] * D_DIM + col];
        float y1 = (float)Ys[(size_t)r1[q] * D_DIM + col];
        out[(size_t)tok * D_DIM + col] = acc[mf][nf][q] + bv + y0 + y1;
      }
    }
  }
}

// ---------------------------------------------------------------- launch
extern "C" void kernel_launch(void* const* d_in, const int* in_sizes, int n_in,
                              void* d_out, int out_size, void* d_ws, size_t ws_size,
                              hipStream_t stream) {
  (void)in_sizes; (void)n_in; (void)out_size; (void)ws_size;
  const float* x    = (const float*)d_in[0];
  const float* gW   = (const float*)d_in[1];
  const float* W1   = (const float*)d_in[2];
  const float* b1   = (const float*)d_in[3];
  const float* W2   = (const float*)d_in[4];
  const float* b2   = (const float*)d_in[5];
  const float* Ws1  = (const float*)d_in[6];
  const float* bs1  = (const float*)d_in[7];
  const float* Ws2  = (const float*)d_in[8];
  const float* bs2  = (const float*)d_in[9];
  const float* rsc  = (const float*)d_in[10];
  float* out = (float*)d_out;

  char* w = (char*)d_ws;
  float*  gateT = (float*)w;  w += (size_t)E_NUM * TOKENS * 4;       // 0.25 MB
  int*    sel   = (int*)w;    w += (size_t)TOKENS * 4;               // 32 KB
  bf16_t* Xb    = (bf16_t*)w; w += (size_t)TOKENS * D_DIM * 2;       // 16.8 MB
  bf16_t* Bt1   = (bf16_t*)w; w += (size_t)N1 * D_DIM * 2;           // 9.4 MB
  bf16_t* Bt2e  = (bf16_t*)w; w += (size_t)9 * D_DIM * H_DIM * 2;    // 9.4 MB
  bf16_t* Hs    = (bf16_t*)w; w += (size_t)HS_ROWS * H_DIM * 2;      // 33.6 MB
  bf16_t* Ys    = (bf16_t*)w; w += (size_t)EXP_ROWS * D_DIM * 2;     // 50.3 MB
  int*    perm  = (int*)w;    w += (size_t)EXP_ROWS * 4;             // 98 KB
  float*  grow  = (float*)w;  w += (size_t)EXP_ROWS * 4;             // 98 KB
  int*    tok2row = (int*)w;  w += (size_t)TOKENS * 2 * 4;           // 64 KB
  int*    padcnt  = (int*)w;                                         // 32 B

  routing_repack_kernel<<<TOKENS / 4 + 32 * 288, 256, 0, stream>>>(
      x, gW, rsc, gateT, sel, Xb, W1, Ws1, W2, Ws2, Bt1, Bt2e);
  listbuild_kernel<<<E_NUM, 256, 0, stream>>>(gateT, sel, perm, grow, tok2row, padcnt);

  gemm1e_kernel<<<dim3(H_DIM / 256, E_NUM * ET256 + TOKENS / 256), dim3(512), 0, stream>>>(
      Xb, Bt1, perm, grow, padcnt, b1, bs1, Hs);
  gemm2e_kernel<<<dim3(D_DIM / 256, E_NUM * ET128), dim3(512), 0, stream>>>(
      Hs, Bt2e, grow, padcnt, b2, Ys);
  gemm2s_kernel<<<dim3(D_DIM / 256, TOKENS / 128), dim3(512), 0, stream>>>(
      Hs, Bt2e, tok2row, bs2, Ys, out);
}

// Round 19
// 142.951 us; speedup vs baseline: 1.0988x; 1.0988x over previous
//
#include <hip/hip_runtime.h>
#include <hip/hip_bf16.h>

// B=4, S=2048, D=1024, E=8, H=512, top-2 + shared expert
#define TOKENS 8192
#define D_DIM  1024
#define E_NUM  8
#define H_DIM  512
#define N1     4608            // E*H + H (Bt1 rows)
#define CAP    3072            // per-expert row capacity (~2048 expected, +26 sigma)
#define ET256  (CAP / 256)     // 12 tiles of 256 per expert segment
#define ET128  (CAP / 128)     // 24 tiles of 128 per expert segment
#define EXP_ROWS (E_NUM * CAP) // 24576 expert rows
#define SH_BASE  EXP_ROWS      // shared segment base in Hs row space
#define HS_ROWS (EXP_ROWS + TOKENS)  // 32768

typedef __bf16 bf16_t;
typedef __bf16 bf16x8 __attribute__((ext_vector_type(8)));
typedef __bf16 bf16x4 __attribute__((ext_vector_type(4)));
typedef float  f32x4  __attribute__((ext_vector_type(4)));

// tanh-form GELU, 7 VALU ops
__device__ __forceinline__ float gelu_fast(float v) {
  float w = v * v;
  float t = __builtin_fmaf(w, 0.10294307f, 2.30258835f);
  float z = v * t;
  float e = __builtin_amdgcn_exp2f(z);
  float r = __builtin_amdgcn_rcpf(e + 1.0f);
  return v - v * r;
}

// ---------------------------------------------------------------- routing (+ fused cast + fused weight repack)
// Routing tail uses monotonicity: top-2 on rs*sigmoid(p) == top-2 on p (order
// flipped if rs<0) -> fp64 COMPARES only, selection bit-identical to the fp64
// score path. Weights: rs cancels -> sigma1/(sigma1+sigma2), two fp32 expf.
__global__ __launch_bounds__(256) void routing_repack_kernel(
    const float* __restrict__ x, const float* __restrict__ gW,
    const float* __restrict__ route_scale, float* __restrict__ gateT,
    int* __restrict__ sel, bf16_t* __restrict__ Xb,
    const float* __restrict__ W1, const float* __restrict__ Ws1,
    const float* __restrict__ W2, const float* __restrict__ Ws2,
    bf16_t* __restrict__ Bt1, bf16_t* __restrict__ Bt2e) {
  const int bid = blockIdx.x;
  if (bid < TOKENS / 4) {
    int tok  = bid * 4 + (threadIdx.x >> 6);
    int lane = threadIdx.x & 63;
    const float* xr = x + (size_t)tok * D_DIM;
    double p[E_NUM];
#pragma unroll
    for (int e = 0; e < E_NUM; ++e) p[e] = 0.0;
    for (int d = lane; d < D_DIM; d += 64) {
      double xv = (double)xr[d];
      const float* g = gW + (size_t)d * E_NUM;
#pragma unroll
      for (int e = 0; e < E_NUM; ++e) p[e] += xv * (double)g[e];
    }
#pragma unroll
    for (int off = 32; off > 0; off >>= 1) {
#pragma unroll
      for (int e = 0; e < E_NUM; ++e) p[e] += __shfl_xor(p[e], off, 64);
    }
    if (lane == 0) {
      const float rs = route_scale[0];
      const bool neg = rs < 0.f;     // sigmoid strictly increasing; rs<0 flips order
      int i1 = 0;
#pragma unroll
      for (int e = 1; e < E_NUM; ++e)
        if (neg ? (p[e] < p[i1]) : (p[e] > p[i1])) i1 = e;
      int i2 = (i1 == 0) ? 1 : 0;
#pragma unroll
      for (int e = 0; e < E_NUM; ++e)
        if (e != i1 && (neg ? (p[e] < p[i2]) : (p[e] > p[i2]))) i2 = e;
      const float s1 = 1.f / (1.f + __expf(-(float)p[i1]));
      const float s2 = 1.f / (1.f + __expf(-(float)p[i2]));
      const float inv = 1.f / (s1 + s2);
      float o[E_NUM];
#pragma unroll
      for (int e = 0; e < E_NUM; ++e) o[e] = 0.f;
      o[i1] = s1 * inv;
      o[i2] = s2 * inv;
#pragma unroll
      for (int e = 0; e < E_NUM; ++e) gateT[(size_t)e * TOKENS + tok] = o[e];
      sel[tok] = i1 * 8 + i2;
    }
    const float4* x4 = (const float4*)xr;
    bf16x4* xb4 = (bf16x4*)(Xb + (size_t)tok * D_DIM);
#pragma unroll
    for (int i = 0; i < 4; ++i) {
      float4 v = x4[i * 64 + lane];
      bf16x4 o = { (bf16_t)v.x, (bf16_t)v.y, (bf16_t)v.z, (bf16_t)v.w };
      xb4[i * 64 + lane] = o;
    }
  } else {
    __shared__ float tile[32][33];
    const int rid = bid - TOKENS / 4;
    const int bx = rid & 31, by = rid >> 5;   // 32 x-blocks, 288 y-blocks
    const int tx = threadIdx.x & 31, ty = threadIdx.x >> 5;
    if (by < 144) {
      const int k0 = bx * 32, n0 = by * 32;
#pragma unroll
      for (int i = 0; i < 4; ++i) {
        int kl = ty + i * 8;
        int n = n0 + tx, k = k0 + kl;
        float v;
        if (n0 < 4096) v = W1[(size_t)(n >> 9) * (D_DIM * H_DIM) + (size_t)k * H_DIM + (n & 511)];
        else           v = Ws1[(size_t)k * H_DIM + (n - 4096)];
        tile[kl][tx] = v;
      }
      __syncthreads();
#pragma unroll
      for (int i = 0; i < 4; ++i) {
        int nl = ty + i * 8;
        Bt1[(size_t)(n0 + nl) * D_DIM + k0 + tx] = (bf16_t)tile[tx][nl];
      }
    } else {
      const int yy = by - 144;
      const int e = yy >> 4;                 // 0..8
      const int h0 = (yy & 15) * 32;
      const int d0 = bx * 32;
#pragma unroll
      for (int i = 0; i < 4; ++i) {
        int hl = ty + i * 8;
        int h = h0 + hl, d = d0 + tx;
        float v = (e < E_NUM) ? W2[((size_t)e * H_DIM + h) * D_DIM + d]
                              : Ws2[(size_t)h * D_DIM + d];
        tile[hl][tx] = v;
      }
      __syncthreads();
#pragma unroll
      for (int i = 0; i < 4; ++i) {
        int dl = ty + i * 8;
        Bt2e[((size_t)e * D_DIM + (d0 + dl)) * H_DIM + h0 + tx] = (bf16_t)tile[tx][dl];
      }
    }
  }
}

// ---------------------------------------------------------------- list build: 8 blocks (1/expert) x 256, pads to x256
__global__ __launch_bounds__(256) void listbuild_kernel(
    const float* __restrict__ gateT, const int* __restrict__ sel,
    int* __restrict__ perm, float* __restrict__ grow,
    int* __restrict__ tok2row, int* __restrict__ padcnt) {
  const int e = blockIdx.x;
  const int tid = threadIdx.x, lane = tid & 63, wid = tid >> 6;
  __shared__ int wsum[4];
  const float* row = gateT + (size_t)e * TOKENS;
  const int base = e * CAP;
  int running = 0;
  float gv = row[tid];                       // prefetch chunk 0
  for (int c = 0; c < TOKENS / 256; ++c) {
    float gv_next = (c + 1 < TOKENS / 256) ? row[(c + 1) * 256 + tid] : 0.f;
    const int tok = c * 256 + tid;
    const bool f = gv > 0.f;
    unsigned long long m = __ballot(f);
    int lanepre = __popcll(m & ((1ull << lane) - 1ull));
    if (lane == 0) wsum[wid] = __popcll(m);
    __syncthreads();
    int wbase = 0;
#pragma unroll
    for (int w2 = 0; w2 < 4; ++w2) if (w2 < wid) wbase += wsum[w2];
    const int tot = wsum[0] + wsum[1] + wsum[2] + wsum[3];
    if (f) {
      const int idx = running + wbase + lanepre;
      if (idx < CAP) {
        perm[base + idx] = tok;
        grow[base + idx] = gv;
        const int s = sel[tok];
        const int other = ((s >> 3) == e) ? (s & 7) : (s >> 3);
        tok2row[tok * 2 + (e > other ? 1 : 0)] = base + idx;
      }
    }
    running += tot;
    __syncthreads();
    gv = gv_next;
  }
  if (running > CAP) running = CAP;
  const int pc = (running + 255) & ~255;     // pad to 256-row tiles (valid for 128-tiles too)
  for (int i = running + tid; i < pc; i += 256) { perm[base + i] = 0; grow[base + i] = 0.f; }
  if (tid == 0) padcnt[e] = pc;
}

__device__ __forceinline__ void gload16(const char* src, char* dst) {
  __builtin_amdgcn_global_load_lds((const __attribute__((address_space(1))) void*)src,
      (__attribute__((address_space(3))) void*)dst, 16, 0, 0);
}

// staging source column byte with slot pre-swizzle (inverse of read swizzle)
__device__ __forceinline__ int swz_src(int lane) {
  return ((lane & 7) ^ ((lane >> 3) & 7)) * 16;
}

// ---------------------------------------------------------------- 256x256 BK=64 8-wave GEMM core (round-11 proven)
__device__ __forceinline__ void gemm_core256(
    const char* ga0, const char* ga1, const char* ga2, const char* ga3,
    const char* gb0, const char* gb1, const char* gb2, const char* gb3,
    int ktiles, char* lds, int wid, int lane, f32x4 (&acc)[8][4]) {
  const int wm = wid >> 2, wn = wid & 3;
  const int lA = lane & 15, kq = lane >> 4;
  const int slot0 = (kq ^ (lA & 7)) * 16;
  const int slot1 = ((4 + kq) ^ (lA & 7)) * 16;

  auto stage8 = [&](int buf, int t) {
    char* dA = lds + buf * 65536 + wid * 1024;
    char* dB = dA + 32768;
    const size_t ko = (size_t)t * 128;
    gload16(ga0 + ko, dA + 0 * 8192);
    gload16(ga1 + ko, dA + 1 * 8192);
    gload16(ga2 + ko, dA + 2 * 8192);
    gload16(ga3 + ko, dA + 3 * 8192);
    gload16(gb0 + ko, dB + 0 * 8192);
    gload16(gb1 + ko, dB + 1 * 8192);
    gload16(gb2 + ko, dB + 2 * 8192);
    gload16(gb3 + ko, dB + 3 * 8192);
  };

  stage8(0, 0);
  for (int t = 0; t < ktiles; ++t) {
    const int b = t & 1;
    asm volatile("s_waitcnt vmcnt(0)" ::: "memory");   // tile-t loads landed (issued 1 tile ago)
    __builtin_amdgcn_s_barrier();                      // landed for ALL waves; t-1 readers retired
    asm volatile("" ::: "memory");
    if (t + 1 < ktiles) stage8(b ^ 1, t + 1);
    const char* Ab = lds + b * 65536 + wm * 16384;
    const char* Bb = lds + b * 65536 + 32768 + (wn >> 1) * 16384 + ((wn & 1) * 64) * 128;
    bf16x8 bfv[4][2];
#pragma unroll
    for (int nf = 0; nf < 4; ++nf) {
      const int rb = (nf * 16 + lA) * 128;
      bfv[nf][0] = *(const bf16x8*)(Bb + rb + slot0);
      bfv[nf][1] = *(const bf16x8*)(Bb + rb + slot1);
    }
#pragma unroll
    for (int qm = 0; qm < 2; ++qm) {
      bf16x8 af[4][2];
#pragma unroll
      for (int i = 0; i < 4; ++i) {
        const int ra = ((qm * 4 + i) * 16 + lA) * 128;
        af[i][0] = *(const bf16x8*)(Ab + ra + slot0);
        af[i][1] = *(const bf16x8*)(Ab + ra + slot1);
      }
      __builtin_amdgcn_s_setprio(1);
#pragma unroll
      for (int s = 0; s < 2; ++s)         // k-slot outer: consecutive MFMAs independent
#pragma unroll
        for (int i = 0; i < 4; ++i)
#pragma unroll
          for (int nf = 0; nf < 4; ++nf)
            acc[qm * 4 + i][nf] = __builtin_amdgcn_mfma_f32_16x16x32_bf16(
                af[i][s], bfv[nf][s], acc[qm * 4 + i][nf], 0, 0, 0);
      __builtin_amdgcn_s_setprio(0);
      __builtin_amdgcn_sched_barrier(0);
    }
  }
}

// ---------------------------------------------------------------- 128x256 BK=64 8-wave core (gemm2e + gemm2s)
__device__ __forceinline__ void gemm_core_s(
    const char* ga, const char* gb,        // per-lane row ptrs, stride 1024B
    int ktiles, char* lds, int wid, int lane, f32x4 (&acc)[4][4]) {
  const int wm = wid >> 2, wn = wid & 3;
  const int lA = lane & 15, kq = lane >> 4;
  const int slot0 = (kq ^ (lA & 7)) * 16;
  const int slot1 = ((4 + kq) ^ (lA & 7)) * 16;

  auto stage6 = [&](int buf, int t) {
    char* base = lds + buf * 49152;
    char* dA = base + wid * 2048;
    char* dB = base + 16384 + wid * 4096;
    const size_t ko = (size_t)t * 128;
    gload16(ga + ko,         dA);
    gload16(ga + 8192 + ko,  dA + 1024);
    gload16(gb + ko,         dB);
    gload16(gb + 8192 + ko,  dB + 1024);
    gload16(gb + 16384 + ko, dB + 2048);
    gload16(gb + 24576 + ko, dB + 3072);
  };

  stage6(0, 0);
  for (int t = 0; t < ktiles; ++t) {
    const int b = t & 1;
    asm volatile("s_waitcnt vmcnt(0)" ::: "memory");
    __builtin_amdgcn_s_barrier();
    asm volatile("" ::: "memory");
    if (t + 1 < ktiles) stage6(b ^ 1, t + 1);
    const char* Ab = lds + b * 49152 + wm * 8192;            // wm*64 rows * 128B
    const char* Bb = lds + b * 49152 + 16384 + wn * 8192;    // wn*64 n-rows * 128B
    bf16x8 bfv[4][2];
#pragma unroll
    for (int nf = 0; nf < 4; ++nf) {
      const int rb = (nf * 16 + lA) * 128;
      bfv[nf][0] = *(const bf16x8*)(Bb + rb + slot0);
      bfv[nf][1] = *(const bf16x8*)(Bb + rb + slot1);
    }
#pragma unroll
    for (int qm = 0; qm < 2; ++qm) {
      bf16x8 af[2][2];
#pragma unroll
      for (int i = 0; i < 2; ++i) {
        const int ra = ((qm * 2 + i) * 16 + lA) * 128;
        af[i][0] = *(const bf16x8*)(Ab + ra + slot0);
        af[i][1] = *(const bf16x8*)(Ab + ra + slot1);
      }
      __builtin_amdgcn_s_setprio(1);
#pragma unroll
      for (int s = 0; s < 2; ++s)
#pragma unroll
        for (int i = 0; i < 2; ++i)
#pragma unroll
          for (int nf = 0; nf < 4; ++nf)
            acc[qm * 2 + i][nf] = __builtin_amdgcn_mfma_f32_16x16x32_bf16(
                af[i][s], bfv[nf][s], acc[qm * 2 + i][nf], 0, 0, 0);
      __builtin_amdgcn_s_setprio(0);
      __builtin_amdgcn_sched_barrier(0);
    }
  }
}

// ---------------------------------------------------------------- GEMM1 (256x256): Hs = gate * gelu(X[perm] @ W1[e]^T + b1)
__global__ __launch_bounds__(512, 2) void gemm1e_kernel(
    const bf16_t* __restrict__ Xb, const bf16_t* __restrict__ Bt1,
    const int* __restrict__ perm, const float* __restrict__ grow,
    const int* __restrict__ padcnt,
    const float* __restrict__ b1, const float* __restrict__ bs1,
    bf16_t* __restrict__ Hs) {
  __shared__ bf16_t sL[65536];           // 128 KB
  const int t = threadIdx.x, wid = t >> 6, lane = t & 63;
  // T1 XCD-bijective swizzle: grid 2x128 = 256 = 8 XCDs x 32.
  const int L = blockIdx.x + 2 * blockIdx.y;
  const int xc = L & 7, ii = L >> 3;
  const int bx = xc >> 2;
  const int by = (xc & 3) * 32 + ii;
  int e, rowbase;
  if (by < E_NUM * ET256) {
    e = by / ET256;
    const int lt = by - e * ET256;
    if (lt * 256 >= padcnt[e]) return;
    rowbase = e * CAP + lt * 256;
  } else {
    e = E_NUM;
    rowbase = SH_BASE + (by - E_NUM * ET256) * 256;
  }
  const int n0 = bx * 256;               // N = 512
  const int rl = wid * 8 + (lane >> 3);
  const int sc = swz_src(lane);
  const char *ga[4], *gb[4];
#pragma unroll
  for (int g = 0; g < 4; ++g) {
    const int r = g * 64 + rl;
    const int tok = (e < E_NUM) ? perm[rowbase + r] : (rowbase - SH_BASE + r);
    ga[g] = (const char*)Xb + (size_t)tok * 2048 + sc;
    gb[g] = (const char*)(Bt1 + (size_t)e * H_DIM * D_DIM) + (size_t)(n0 + r) * 2048 + sc;
  }
  f32x4 acc[8][4];
#pragma unroll
  for (int i = 0; i < 8; ++i)
#pragma unroll
    for (int j = 0; j < 4; ++j) acc[i][j] = (f32x4){0.f, 0.f, 0.f, 0.f};
  gemm_core256(ga[0], ga[1], ga[2], ga[3], gb[0], gb[1], gb[2], gb[3],
               D_DIM / 64, (char*)sL, wid, lane, acc);

  const int wm = wid >> 2, wn = wid & 3, lA = lane & 15;
  const float* bias = (e < E_NUM) ? (b1 + e * H_DIM) : bs1;
#pragma unroll
  for (int mf = 0; mf < 8; ++mf) {
    const int rloc = wm * 128 + mf * 16 + (lane >> 4) * 4;
    float gr[4];
#pragma unroll
    for (int q = 0; q < 4; ++q)
      gr[q] = (e < E_NUM) ? grow[rowbase + rloc + q] : 1.0f;
#pragma unroll
    for (int nf = 0; nf < 4; ++nf) {
      const int col = n0 + wn * 64 + nf * 16 + lA;
      const float bv = bias[col];
#pragma unroll
      for (int q = 0; q < 4; ++q) {
        float v = gelu_fast(acc[mf][nf][q] + bv);
        Hs[(size_t)(rowbase + rloc + q) * H_DIM + col] = (bf16_t)(v * gr[q]);
      }
    }
  }
}

// ---------------------------------------------------------------- GEMM2 expert tiles (128x256): Ys(bf16) = acc + grow*b2[e]
__global__ __launch_bounds__(512, 2) void gemm2e_kernel(
    const bf16_t* __restrict__ Hs, const bf16_t* __restrict__ Bt2e,
    const float* __restrict__ grow, const int* __restrict__ padcnt,
    const float* __restrict__ b2, bf16_t* __restrict__ Ys) {
  __shared__ bf16_t sL[49152];           // 96 KB
  const int t = threadIdx.x, wid = t >> 6, lane = t & 63;
  // T1 swizzle: grid 4x192 = 768 = 8 x 96
  const int L = blockIdx.x + 4 * blockIdx.y;
  const int xc = L & 7, ii = L >> 3;
  const int bx = xc >> 1;                // 0..3
  const int by = (xc & 1) * 96 + ii;     // 0..191
  const int e = by / ET128;
  const int lt = by - e * ET128;
  if (lt * 128 >= padcnt[e]) return;
  const int rowbase = e * CAP + lt * 128;
  const int n0 = bx * 256;               // N = 1024
  const int sc = swz_src(lane);
  const char* ga = (const char*)Hs + (size_t)(rowbase + wid * 16 + (lane >> 3)) * 1024 + sc;
  const char* gb = (const char*)(Bt2e + (size_t)e * D_DIM * H_DIM)
                 + (size_t)(n0 + wid * 32 + (lane >> 3)) * 1024 + sc;
  f32x4 acc[4][4];
#pragma unroll
  for (int i = 0; i < 4; ++i)
#pragma unroll
    for (int j = 0; j < 4; ++j) acc[i][j] = (f32x4){0.f, 0.f, 0.f, 0.f};
  gemm_core_s(ga, gb, H_DIM / 64, (char*)sL, wid, lane, acc);

  const int wm = wid >> 2, wn = wid & 3, lA = lane & 15;
  const float* bb = b2 + (size_t)e * D_DIM;
#pragma unroll
  for (int mf = 0; mf < 4; ++mf) {
    const int rloc = wm * 64 + mf * 16 + (lane >> 4) * 4;
    float gr[4];
#pragma unroll
    for (int q = 0; q < 4; ++q) gr[q] = grow[rowbase + rloc + q];
#pragma unroll
    for (int nf = 0; nf < 4; ++nf) {
      const int col = n0 + wn * 64 + nf * 16 + lA;
      const float bv = bb[col];
#pragma unroll
      for (int q = 0; q < 4; ++q)
        Ys[(size_t)(rowbase + rloc + q) * D_DIM + col] = (bf16_t)(acc[mf][nf][q] + gr[q] * bv);
    }
  }
}

// ---------------------------------------------------------------- GEMM2 shared tiles + combine (128x256 tile, 256 blocks)
__global__ __launch_bounds__(512, 2) void gemm2s_kernel(
    const bf16_t* __restrict__ Hs, const bf16_t* __restrict__ Bt2e,
    const int* __restrict__ tok2row, const float* __restrict__ bs2,
    const bf16_t* __restrict__ Ys, float* __restrict__ out) {
  __shared__ bf16_t sL[49152];           // 96 KB
  const int t = threadIdx.x, wid = t >> 6, lane = t & 63;
  // T1 swizzle: grid 4x64 = 256 = 8 x 32
  const int L = blockIdx.x + 4 * blockIdx.y;
  const int xc = L & 7, ii = L >> 3;
  const int bx = xc >> 1;                // 0..3
  const int by = (xc & 1) * 32 + ii;     // 0..63
  const int tokbase = by * 128;
  const int rowbase = SH_BASE + tokbase;
  const int n0 = bx * 256;               // N = 1024
  const int sc = swz_src(lane);
  const char* ga = (const char*)Hs + (size_t)(rowbase + wid * 16 + (lane >> 3)) * 1024 + sc;
  const char* gb = (const char*)(Bt2e + (size_t)E_NUM * D_DIM * H_DIM)
                 + (size_t)(n0 + wid * 32 + (lane >> 3)) * 1024 + sc;
  f32x4 acc[4][4];
#pragma unroll
  for (int i = 0; i < 4; ++i)
#pragma unroll
    for (int j = 0; j < 4; ++j) acc[i][j] = (f32x4){0.f, 0.f, 0.f, 0.f};
  gemm_core_s(ga, gb, H_DIM / 64, (char*)sL, wid, lane, acc);

  const int wm = wid >> 2, wn = wid & 3, lA = lane & 15;
#pragma unroll
  for (int mf = 0; mf < 4; ++mf) {
    const int rloc = wm * 64 + mf * 16 + (lane >> 4) * 4;
    int r0[4], r1[4];
#pragma unroll
    for (int q = 0; q < 4; ++q) {
      const int tok = tokbase + rloc + q;
      r0[q] = tok2row[tok * 2];
      r1[q] = tok2row[tok * 2 + 1];
    }
#pragma unroll
    for (int nf = 0; nf < 4; ++nf) {
      const int col = n0 + wn * 64 + nf * 16 + lA;
      const float bv = bs2[col];
#pragma unroll
      for (int q = 0; q < 4; ++q) {
        const int tok = tokbase + rloc + q;
        float y0 = (float)Ys[(size_t)r0[q] * D_DIM + col];
        float y1 = (float)Ys[(size_t)r1[q] * D_DIM + col];
        out[(size_t)tok * D_DIM + col] = acc[mf][nf][q] + bv + y0 + y1;
      }
    }
  }
}

// ---------------------------------------------------------------- launch
extern "C" void kernel_launch(void* const* d_in, const int* in_sizes, int n_in,
                              void* d_out, int out_size, void* d_ws, size_t ws_size,
                              hipStream_t stream) {
  (void)in_sizes; (void)n_in; (void)out_size; (void)ws_size;
  const float* x    = (const float*)d_in[0];
  const float* gW   = (const float*)d_in[1];
  const float* W1   = (const float*)d_in[2];
  const float* b1   = (const float*)d_in[3];
  const float* W2   = (const float*)d_in[4];
  const float* b2   = (const float*)d_in[5];
  const float* Ws1  = (const float*)d_in[6];
  const float* bs1  = (const float*)d_in[7];
  const float* Ws2  = (const float*)d_in[8];
  const float* bs2  = (const float*)d_in[9];
  const float* rsc  = (const float*)d_in[10];
  float* out = (float*)d_out;

  char* w = (char*)d_ws;
  float*  gateT = (float*)w;  w += (size_t)E_NUM * TOKENS * 4;       // 0.25 MB
  int*    sel   = (int*)w;    w += (size_t)TOKENS * 4;               // 32 KB
  bf16_t* Xb    = (bf16_t*)w; w += (size_t)TOKENS * D_DIM * 2;       // 16.8 MB
  bf16_t* Bt1   = (bf16_t*)w; w += (size_t)N1 * D_DIM * 2;           // 9.4 MB
  bf16_t* Bt2e  = (bf16_t*)w; w += (size_t)9 * D_DIM * H_DIM * 2;    // 9.4 MB
  bf16_t* Hs    = (bf16_t*)w; w += (size_t)HS_ROWS * H_DIM * 2;      // 33.6 MB
  bf16_t* Ys    = (bf16_t*)w; w += (size_t)EXP_ROWS * D_DIM * 2;     // 50.3 MB
  int*    perm  = (int*)w;    w += (size_t)EXP_ROWS * 4;             // 98 KB
  float*  grow  = (float*)w;  w += (size_t)EXP_ROWS * 4;             // 98 KB
  int*    tok2row = (int*)w;  w += (size_t)TOKENS * 2 * 4;           // 64 KB
  int*    padcnt  = (int*)w;                                         // 32 B

  routing_repack_kernel<<<TOKENS / 4 + 32 * 288, 256, 0, stream>>>(
      x, gW, rsc, gateT, sel, Xb, W1, Ws1, W2, Ws2, Bt1, Bt2e);
  listbuild_kernel<<<E_NUM, 256, 0, stream>>>(gateT, sel, perm, grow, tok2row, padcnt);

  gemm1e_kernel<<<dim3(H_DIM / 256, E_NUM * ET256 + TOKENS / 256), dim3(512), 0, stream>>>(
      Xb, Bt1, perm, grow, padcnt, b1, bs1, Hs);
  gemm2e_kernel<<<dim3(D_DIM / 256, E_NUM * ET128), dim3(512), 0, stream>>>(
      Hs, Bt2e, grow, padcnt, b2, Ys);
  gemm2s_kernel<<<dim3(D_DIM / 256, TOKENS / 128), dim3(512), 0, stream>>>(
      Hs, Bt2e, tok2row, bs2, Ys, out);
}